// Round 5
// baseline (350.835 us; speedup 1.0000x reference)
//
#include <hip/hip_runtime.h>
#include <stdint.h>

typedef unsigned short u16;

#define D_MODEL 2048
#define HEADS 16
#define HDIM 128
#define SEQ 2048
#define BATCH 2
#define NROWS (BATCH*SEQ)          // 4096
#define QKV_N (D_MODEL + 2*HDIM)   // 2304

typedef __attribute__((ext_vector_type(8))) short bf16x8;
typedef __attribute__((ext_vector_type(4))) float f32x4;

__device__ inline u16 f2bf(float f) {
  union { float f; uint32_t u; } v; v.f = f;
  uint32_t r = v.u + 0x7FFFu + ((v.u >> 16) & 1u);
  return (u16)(r >> 16);
}
__device__ inline u16 f2bf_fast(float f) {  // round-to-nearest (no tie fix)
  union { float f; uint32_t u; } v; v.f = f;
  return (u16)((v.u + 0x8000u) >> 16);
}

__device__ inline void gload_lds16(const void* g, void* l) {
  __builtin_amdgcn_global_load_lds(
      (const __attribute__((address_space(1))) unsigned int*)g,
      (__attribute__((address_space(3))) unsigned int*)l, 16, 0, 0);
}

// ---------------- fused x fp32->bf16 + bias pack ----------------
__global__ void cvt_bias(const float* __restrict__ s, u16* __restrict__ d,
                         const float* __restrict__ bq, const float* __restrict__ bk,
                         const float* __restrict__ bv, float* __restrict__ biasq) {
  const int bid = blockIdx.x;
  if (bid < 8192) {
    int i = bid * 256 + threadIdx.x;   // covers 4096*2048/4 exactly
    float4 f = ((const float4*)s)[i];
    ushort4 u;
    u.x = f2bf(f.x); u.y = f2bf(f.y); u.z = f2bf(f.z); u.w = f2bf(f.w);
    ((ushort4*)d)[i] = u;
  } else {
    for (int i = threadIdx.x; i < QKV_N; i += 256)
      biasq[i] = (i < D_MODEL) ? bq[i]
               : ((i < D_MODEL + HDIM) ? bk[i - D_MODEL] : bv[i - D_MODEL - HDIM]);
  }
}

// ---------------- fused transpose+cvt for all weights ----------------
// virtual col space: [0,2048)=wq, [2048,2176)=wk, [2176,2304)=wv -> wqkvT rows
//                    [2304,4352)=wo -> woT rows
__global__ void transpose_all(const float* __restrict__ wq, const float* __restrict__ wk,
                              const float* __restrict__ wv, const float* __restrict__ wo,
                              u16* __restrict__ wqkvT, u16* __restrict__ woT) {
  __shared__ float t[32][33];
  const int n0v = blockIdx.x * 32, k0 = blockIdx.y * 32;
  const float* src; int N, n0, drow; u16* dst;
  if (n0v < 2048)      { src = wq; N = 2048; n0 = n0v;        dst = wqkvT; drow = n0v; }
  else if (n0v < 2176) { src = wk; N = 128;  n0 = n0v - 2048; dst = wqkvT; drow = n0v; }
  else if (n0v < 2304) { src = wv; N = 128;  n0 = n0v - 2176; dst = wqkvT; drow = n0v; }
  else                 { src = wo; N = 2048; n0 = n0v - 2304; dst = woT;   drow = n0v - 2304; }
  const int tx = threadIdx.x, ty = threadIdx.y;  // 32 x 8
#pragma unroll
  for (int i = 0; i < 4; i++)
    t[ty + 8*i][tx] = src[(size_t)(k0 + ty + 8*i) * N + n0 + tx];
  __syncthreads();
#pragma unroll
  for (int i = 0; i < 4; i++)
    dst[(size_t)(drow + ty + 8*i) * D_MODEL + k0 + tx] = f2bf(t[tx][ty + 8*i]);
}

// ---------------- bf16 GEMM v2: double-buffered LDS, ONE barrier per K-step ----
// C = A[M,K] * BT[N,K]^T + bias. 128x128 tile, BK=32, 4 waves (64x64 each).
#define BM 128
#define BN 128
#define BK 32

__global__ __launch_bounds__(256) void gemm_bt(
    const u16* __restrict__ A, const u16* __restrict__ BT,
    const float* __restrict__ bias,
    u16* __restrict__ Cb, float* __restrict__ Cf,
    u16* __restrict__ vT,
    int M, int Nld, int colOff, int tilesN, int K) {
  __shared__ __align__(16) u16 sA[2][BM * BK];   // 2 x 8 KB
  __shared__ __align__(16) u16 sB[2][BN * BK];   // 2 x 8 KB
  const int tid = threadIdx.x;
  const int wave = tid >> 6, lane = tid & 63;
  const int bm = blockIdx.x / tilesN, bn = blockIdx.x % tilesN;
  const int m0 = bm * BM, n0 = bn * BN;
  const int wm = (wave & 1) * 64, wn = (wave >> 1) * 64;
  const int l16 = lane & 15, kq = (lane >> 4) * 8;

  f32x4 acc[4][4] = {};
  const int srow = lane >> 2, scol = (lane & 3) * 8;

#define GDMA(i, buf)                                                           \
  {                                                                            \
    const int _k0 = (i) * BK;                                                  \
    _Pragma("unroll") for (int c = 0; c < 2; c++) {                            \
      const int chunk = wave * 2 + c;                                          \
      const int row = chunk * 16 + srow;                                       \
      gload_lds16(&A[(size_t)(m0 + row) * K + _k0 + scol],                     \
                  &sA[buf][chunk * 512]);                                      \
      gload_lds16(&BT[(size_t)(n0 + row) * K + _k0 + scol],                    \
                  &sB[buf][chunk * 512]);                                      \
    }                                                                          \
  }

  const int NI = K / BK;
  GDMA(0, 0);
  for (int i = 0; i < NI; i++) {
    const int cur = i & 1;
    __syncthreads();                 // drains own DMA(i) (issued a full phase ago)
    if (i + 1 < NI) GDMA(i + 1, cur ^ 1);
    bf16x8 af[4], bfr[4];
#pragma unroll
    for (int mb = 0; mb < 4; ++mb) af[mb]  = *(const bf16x8*)&sA[cur][(wm + mb*16 + l16) * BK + kq];
#pragma unroll
    for (int nb = 0; nb < 4; ++nb) bfr[nb] = *(const bf16x8*)&sB[cur][(wn + nb*16 + l16) * BK + kq];
#pragma unroll
    for (int mb = 0; mb < 4; ++mb)
#pragma unroll
      for (int nb = 0; nb < 4; ++nb)
        acc[mb][nb] = __builtin_amdgcn_mfma_f32_16x16x32_bf16(af[mb], bfr[nb], acc[mb][nb], 0, 0, 0);
  }
#undef GDMA

  // epilogue: C/D layout col=lane&15, row=(lane>>4)*4+r
#pragma unroll
  for (int mb = 0; mb < 4; ++mb) {
#pragma unroll
    for (int nb = 0; nb < 4; ++nb) {
      const int gnL = n0 + wn + nb * 16 + l16;    // local col (BT/bias index)
      const int gn = colOff + gnL;                // global output col
      const float bb = bias ? bias[gnL] : 0.0f;
#pragma unroll
      for (int r = 0; r < 4; ++r) {
        const int gm = m0 + wm + mb * 16 + (lane >> 4) * 4 + r;
        const float v = acc[mb][nb][r] + bb;
        if (Cf) {
          Cf[(size_t)gm * Nld + gn] = v;
        } else {
          const u16 u = f2bf(v);
          Cb[(size_t)gm * Nld + gn] = u;
          if (vT && gn >= D_MODEL + HDIM) {       // V^T side-write [b][d][s]
            const int bi = gm >> 11, si = gm & 2047;
            vT[((size_t)bi * HDIM + (gn - D_MODEL - HDIM)) * SEQ + si] = u;
          }
        }
      }
    }
  }
}

// ---------------- flash-style MQA attention v4 (unchanged from R4) ----------------
__global__ __launch_bounds__(256) void mqa_attn(
    const u16* __restrict__ qkv, const u16* __restrict__ vT, u16* __restrict__ ctx) {
  __shared__ __align__(16) u16 sK[2][64 * 128];  // [buf][key][chunk16 ^ (key&15)]
  __shared__ __align__(16) u16 sV[128 * 64];     // [d][chunk16 ^ (d&7)]
  __shared__ __align__(16) u16 sP[4][32 * 64];   // per-wave, swizzled pairs
  const int tid = threadIdx.x, wave = tid >> 6, lane = tid & 63;
  const int qt = blockIdx.x & 15;
  const int h  = (blockIdx.x >> 4) & 15;
  const int b  = blockIdx.x >> 8;
  const int bS = b * SEQ;
  const int q0 = qt * 128 + wave * 32;
  const int l16 = lane & 15, quad = lane >> 4;
  const int sw = l16 & 7;
  u16* myP = &sP[wave][0];

  bf16x8 qf[2][4];
#pragma unroll
  for (int mb = 0; mb < 2; mb++)
#pragma unroll
    for (int kc = 0; kc < 4; kc++)
      qf[mb][kc] = *(const bf16x8*)&qkv[(size_t)(bS + q0 + mb*16 + l16) * QKV_N
                                        + h*HDIM + kc*32 + quad*8];

  f32x4 o[2][8] = {};
  float lrow[2] = {0.f, 0.f};
  const float sc2 = 0.08838834764831845f * 1.4426950408889634f;

  const u16* Kbase = qkv + (size_t)bS * QKV_N + D_MODEL;
  const u16* Vbase = vT + (size_t)b * HDIM * SEQ;

  const int kRowIn = lane >> 4;
  const int kChS   = lane & 15;
  const int vRowIn = lane >> 3;
  const int vChL   = (lane & 7) ^ (lane >> 3);

#define DMA_K(t, dst)                                                          \
  {                                                                            \
    const int _sk = (t) * 64;                                                  \
    _Pragma("unroll") for (int j = 0; j < 4; j++) {                            \
      const int i = wave * 4 + j;                                              \
      const int krow = i * 4 + kRowIn;                                         \
      const int kcl = kChS ^ (krow & 15);                                      \
      gload_lds16(&Kbase[(size_t)(_sk + krow) * QKV_N + kcl * 8],              \
                  &(dst)[i * 512]);                                            \
    }                                                                          \
  }
#define DMA_V(t)                                                               \
  {                                                                            \
    const int _sk = (t) * 64;                                                  \
    _Pragma("unroll") for (int j = 0; j < 4; j++) {                            \
      const int i = wave * 4 + j;                                              \
      const int d = i * 8 + vRowIn;                                            \
      gload_lds16(&Vbase[(size_t)d * SEQ + _sk + vChL * 8], &sV[i * 512]);     \
    }                                                                          \
  }

  DMA_K(0, sK[0]);
  DMA_V(0);
  __syncthreads();

  const int T = SEQ / 64;
  for (int t = 0; t < T; ++t) {
    const int cur = t & 1;
    if (t + 1 < T) DMA_K(t + 1, sK[cur ^ 1]);

    f32x4 sc[2][4];
#pragma unroll
    for (int nb = 0; nb < 4; nb++) {
      bf16x8 kf[4];
#pragma unroll
      for (int kc = 0; kc < 4; kc++)
        kf[kc] = *(const bf16x8*)&sK[cur][(nb*16 + l16) * 128 + (((kc*4 + quad) ^ l16) * 8)];
#pragma unroll
      for (int mb = 0; mb < 2; mb++) {
        f32x4 a = {0.f, 0.f, 0.f, 0.f};
#pragma unroll
        for (int kc = 0; kc < 4; kc++)
          a = __builtin_amdgcn_mfma_f32_16x16x32_bf16(kf[kc], qf[mb][kc], a, 0, 0, 0);
        sc[mb][nb] = a;
      }
    }

#pragma unroll
    for (int mb = 0; mb < 2; mb++)
#pragma unroll
      for (int nb = 0; nb < 4; nb++) {
        float p0 = __builtin_amdgcn_exp2f(sc[mb][nb][0] * sc2);
        float p1 = __builtin_amdgcn_exp2f(sc[mb][nb][1] * sc2);
        float p2 = __builtin_amdgcn_exp2f(sc[mb][nb][2] * sc2);
        float p3 = __builtin_amdgcn_exp2f(sc[mb][nb][3] * sc2);
        lrow[mb] += (p0 + p1) + (p2 + p3);
        uint32_t lo = (uint32_t)f2bf_fast(p0) | ((uint32_t)f2bf_fast(p1) << 16);
        uint32_t hi = (uint32_t)f2bf_fast(p2) | ((uint32_t)f2bf_fast(p3) << 16);
        uint2 w; w.x = lo; w.y = hi;
        const int pr = (nb*2 + (quad >> 1)) ^ sw;
        *(uint2*)&myP[(mb*16 + l16) * 64 + pr * 8 + (quad & 1) * 4] = w;
      }

    __syncthreads();

    bf16x8 pf[2][2];
#pragma unroll
    for (int mb = 0; mb < 2; mb++)
#pragma unroll
      for (int kc = 0; kc < 2; kc++)
        pf[mb][kc] = *(const bf16x8*)&myP[(mb*16 + l16) * 64 + (((kc*4 + quad) ^ sw) * 8)];
#pragma unroll
    for (int nb = 0; nb < 8; nb++) {
      bf16x8 vf[2];
#pragma unroll
      for (int kc = 0; kc < 2; kc++)
        vf[kc] = *(const bf16x8*)&sV[(nb*16 + l16) * 64 + (((kc*4 + quad) ^ (l16 & 7)) * 8)];
#pragma unroll
      for (int mb = 0; mb < 2; mb++)
#pragma unroll
        for (int kc = 0; kc < 2; kc++)
          o[mb][nb] = __builtin_amdgcn_mfma_f32_16x16x32_bf16(pf[mb][kc], vf[kc], o[mb][nb], 0, 0, 0);
    }

    __syncthreads();
    if (t + 1 < T) DMA_V(t + 1);
  }

#pragma unroll
  for (int mb = 0; mb < 2; mb++) {
    lrow[mb] += __shfl_xor(lrow[mb], 16, 64);
    lrow[mb] += __shfl_xor(lrow[mb], 32, 64);
  }
  float invl[2][4];
#pragma unroll
  for (int mb = 0; mb < 2; mb++)
#pragma unroll
    for (int r = 0; r < 4; r++)
      invl[mb][r] = 1.0f / __shfl(lrow[mb], quad * 4 + r, 64);

#pragma unroll
  for (int mb = 0; mb < 2; mb++)
#pragma unroll
    for (int nb = 0; nb < 8; nb++)
#pragma unroll
      for (int r = 0; r < 4; r++) {
        const int gq = q0 + mb*16 + quad*4 + r;
        const int gd = h * HDIM + nb*16 + l16;
        ctx[(size_t)(bS + gq) * D_MODEL + gd] = f2bf(o[mb][nb][r] * invl[mb][r]);
      }
}

// ---------------- launch ----------------
extern "C" void kernel_launch(void* const* d_in, const int* in_sizes, int n_in,
                              void* d_out, int out_size, void* d_ws, size_t ws_size,
                              hipStream_t stream) {
  const float* x  = (const float*)d_in[0];
  const float* wq = (const float*)d_in[1];
  const float* bq = (const float*)d_in[2];
  const float* wk = (const float*)d_in[3];
  const float* bk = (const float*)d_in[4];
  const float* wv = (const float*)d_in[5];
  const float* bv = (const float*)d_in[6];
  const float* wo = (const float*)d_in[7];
  const float* bo = (const float*)d_in[8];
  float* out = (float*)d_out;
  char* ws = (char*)d_ws;

  u16*   xb    = (u16*)(ws + 0);          // [4096,2048] bf16
  u16*   wqkvT = (u16*)(ws + 16777216);   // [2304,2048] bf16
  u16*   woT   = (u16*)(ws + 26214400);   // [2048,2048] bf16
  u16*   qkv   = (u16*)(ws + 34603008);   // [4096,2304] bf16
  u16*   vT    = (u16*)(ws + 53477376);   // [2,128,2048] bf16
  u16*   ctx   = (u16*)(ws + 54525952);   // [4096,2048] bf16
  float* biasq = (float*)(ws + 71303168); // [2304] f32

  cvt_bias<<<8193, 256, 0, stream>>>(x, xb, bq, bk, bv, biasq);
  transpose_all<<<dim3(136, 64), dim3(32, 8), 0, stream>>>(wq, wk, wv, wo, wqkvT, woT);

  // Q projection: N=2048, balanced 512 blocks (2/CU)
  gemm_bt<<<32 * 16, 256, 0, stream>>>(xb, wqkvT, biasq, qkv, nullptr, nullptr,
                                       NROWS, QKV_N, 0, 16, D_MODEL);
  // KV projection: N=256, 64 blocks
  gemm_bt<<<32 * 2, 256, 0, stream>>>(xb, wqkvT + (size_t)D_MODEL * D_MODEL,
                                      biasq + D_MODEL, qkv, nullptr, vT,
                                      NROWS, QKV_N, D_MODEL, 2, D_MODEL);
  mqa_attn<<<BATCH * HEADS * (SEQ / 128), 256, 0, stream>>>(qkv, vT, ctx);
  gemm_bt<<<32 * 16, 256, 0, stream>>>(ctx, woT, bo, nullptr, out, nullptr,
                                       NROWS, D_MODEL, 0, 16, D_MODEL);
}

// Round 6
// 300.598 us; speedup vs baseline: 1.1671x; 1.1671x over previous
//
#include <hip/hip_runtime.h>
#include <stdint.h>

typedef unsigned short u16;

#define D_MODEL 2048
#define HEADS 16
#define HDIM 128
#define SEQ 2048
#define BATCH 2
#define NROWS (BATCH*SEQ)          // 4096
#define QKV_N (D_MODEL + 2*HDIM)   // 2304

typedef __attribute__((ext_vector_type(8))) short bf16x8;
typedef __attribute__((ext_vector_type(4))) float f32x4;

__device__ inline u16 f2bf(float f) {
  union { float f; uint32_t u; } v; v.f = f;
  uint32_t r = v.u + 0x7FFFu + ((v.u >> 16) & 1u);
  return (u16)(r >> 16);
}
__device__ inline u16 f2bf_fast(float f) {
  union { float f; uint32_t u; } v; v.f = f;
  return (u16)((v.u + 0x8000u) >> 16);
}

__device__ inline void gload_lds16(const void* g, void* l) {
  __builtin_amdgcn_global_load_lds(
      (const __attribute__((address_space(1))) unsigned int*)g,
      (__attribute__((address_space(3))) unsigned int*)l, 16, 0, 0);
}

// ---------------- fused prep: x cvt + all-weight transpose + bias pack ------
// grid: [0,8192) cvt x ; [8192,16896) transpose ; 16896 bias
__global__ void prep_all(const float* __restrict__ x, u16* __restrict__ xb,
                         const float* __restrict__ wq, const float* __restrict__ wk,
                         const float* __restrict__ wv, const float* __restrict__ wo,
                         u16* __restrict__ wqkvT, u16* __restrict__ woT,
                         const float* __restrict__ bq, const float* __restrict__ bk,
                         const float* __restrict__ bv, float* __restrict__ biasq) {
  const int bid = blockIdx.x, tid = threadIdx.x;
  if (bid < 8192) {
    int i = bid * 256 + tid;
    float4 f = ((const float4*)x)[i];
    ushort4 u;
    u.x = f2bf(f.x); u.y = f2bf(f.y); u.z = f2bf(f.z); u.w = f2bf(f.w);
    ((ushort4*)xb)[i] = u;
  } else if (bid < 16896) {
    __shared__ float t[32][33];
    const int b2 = bid - 8192;
    const int n0v = (b2 % 136) * 32, k0 = (b2 / 136) * 32;
    const float* src; int N, n0, drow; u16* dst;
    if (n0v < 2048)      { src = wq; N = 2048; n0 = n0v;        dst = wqkvT; drow = n0v; }
    else if (n0v < 2176) { src = wk; N = 128;  n0 = n0v - 2048; dst = wqkvT; drow = n0v; }
    else if (n0v < 2304) { src = wv; N = 128;  n0 = n0v - 2176; dst = wqkvT; drow = n0v; }
    else                 { src = wo; N = 2048; n0 = n0v - 2304; dst = woT;   drow = n0v - 2304; }
    const int tx = tid & 31, ty = tid >> 5;
#pragma unroll
    for (int i = 0; i < 4; i++)
      t[ty + 8*i][tx] = src[(size_t)(k0 + ty + 8*i) * N + n0 + tx];
    __syncthreads();
#pragma unroll
    for (int i = 0; i < 4; i++)
      dst[(size_t)(drow + ty + 8*i) * D_MODEL + k0 + tx] = f2bf(t[tx][ty + 8*i]);
  } else {
    for (int i = tid; i < QKV_N; i += 256)
      biasq[i] = (i < D_MODEL) ? bq[i]
               : ((i < D_MODEL + HDIM) ? bk[i - D_MODEL] : bv[i - D_MODEL - HDIM]);
  }
}

// ---------------- bf16 GEMM, BK=64, XOR-swizzled LDS --------------------------
// C = A[M,K]*BT[N,K]^T + bias. 128x128 tile, 4 waves (64x64 each).
// LDS row = 64 elems (8 chunks of 16B); chunk stored at (chunk ^ (row&7)).
// DB=true: double-buffered (64 KB), 1 barrier/iter, drain covered by compute.
// DB=false: single-buffered (32 KB), 2 barriers/iter, 3 blocks/CU possible.
#define BM 128
#define BN 128
#define BKK 64

template <bool DB>
__global__ __launch_bounds__(256) void gemm_bt(
    const u16* __restrict__ A, const u16* __restrict__ BT,
    const float* __restrict__ bias,
    u16* __restrict__ Cb, float* __restrict__ Cf,
    u16* __restrict__ vT,
    int M, int N, int tilesN, int K) {
  __shared__ __align__(16) u16 sA[DB ? 2 : 1][BM * BKK];   // 16 KB each
  __shared__ __align__(16) u16 sB[DB ? 2 : 1][BN * BKK];
  const int tid = threadIdx.x;
  const int wave = tid >> 6, lane = tid & 63;
  const int bm = blockIdx.x / tilesN, bn = blockIdx.x % tilesN;
  const int m0 = bm * BM, n0 = bn * BN;
  const int wm = (wave & 1) * 64, wn = (wave >> 1) * 64;
  const int l16 = lane & 15, quad = lane >> 4;

  f32x4 acc[4][4] = {};

  // DMA map: op i (0..15) covers rows i*8 + (lane>>3); global chunk = (lane&7)^(lane>>3)
  const int dRow = lane >> 3;
  const int dCol = ((lane & 7) ^ (lane >> 3)) * 8;

#define GDMA(i, buf)                                                           \
  {                                                                            \
    const int _k0 = (i) * BKK;                                                 \
    _Pragma("unroll") for (int c = 0; c < 4; c++) {                            \
      const int op = wave * 4 + c;                                             \
      const int row = op * 8 + dRow;                                           \
      gload_lds16(&A[(size_t)(m0 + row) * K + _k0 + dCol], &sA[buf][op * 512]);\
      gload_lds16(&BT[(size_t)(n0 + row) * K + _k0 + dCol], &sB[buf][op * 512]);\
    }                                                                          \
  }

  const int NI = K / BKK;
  GDMA(0, 0);
  for (int i = 0; i < NI; i++) {
    const int cur = DB ? (i & 1) : 0;
    __syncthreads();                       // drain DMA(i)
    if (DB && i + 1 < NI) GDMA(i + 1, cur ^ 1);
#pragma unroll
    for (int kk2 = 0; kk2 < 2; kk2++) {    // K halves: kk = kk2*32
      bf16x8 af[4], bfr[4];
#pragma unroll
      for (int mb = 0; mb < 4; ++mb) {
        const int R = wm + mb * 16 + l16;
        const int s = (kk2 * 4 + quad) ^ (l16 & 7);
        af[mb] = *(const bf16x8*)&sA[cur][R * BKK + s * 8];
      }
#pragma unroll
      for (int nb = 0; nb < 4; ++nb) {
        const int R = wn + nb * 16 + l16;
        const int s = (kk2 * 4 + quad) ^ (l16 & 7);
        bfr[nb] = *(const bf16x8*)&sB[cur][R * BKK + s * 8];
      }
#pragma unroll
      for (int mb = 0; mb < 4; ++mb)
#pragma unroll
        for (int nb = 0; nb < 4; ++nb)
          acc[mb][nb] = __builtin_amdgcn_mfma_f32_16x16x32_bf16(af[mb], bfr[nb], acc[mb][nb], 0, 0, 0);
    }
    if (!DB) {
      __syncthreads();                     // all readers done with the buffer
      if (i + 1 < NI) GDMA(i + 1, 0);
    }
  }
#undef GDMA

  // epilogue: C/D layout col=lane&15, row=(lane>>4)*4+r
#pragma unroll
  for (int mb = 0; mb < 4; ++mb) {
#pragma unroll
    for (int nb = 0; nb < 4; ++nb) {
      const int gn = n0 + wn + nb * 16 + l16;
      const float bb = bias ? bias[gn] : 0.0f;
#pragma unroll
      for (int r = 0; r < 4; ++r) {
        const int gm = m0 + wm + mb * 16 + quad * 4 + r;
        const float v = acc[mb][nb][r] + bb;
        if (Cf) {
          Cf[(size_t)gm * N + gn] = v;
        } else {
          const u16 u = f2bf(v);
          Cb[(size_t)gm * N + gn] = u;
          if (vT && gn >= D_MODEL + HDIM) {
            const int bi = gm >> 11, si = gm & 2047;
            vT[((size_t)bi * HDIM + (gn - D_MODEL - HDIM)) * SEQ + si] = u;
          }
        }
      }
    }
  }
}

// ---------------- flash-style MQA attention (FROZEN from R4) ----------------
__global__ __launch_bounds__(256) void mqa_attn(
    const u16* __restrict__ qkv, const u16* __restrict__ vT, u16* __restrict__ ctx) {
  __shared__ __align__(16) u16 sK[2][64 * 128];
  __shared__ __align__(16) u16 sV[128 * 64];
  __shared__ __align__(16) u16 sP[4][32 * 64];
  const int tid = threadIdx.x, wave = tid >> 6, lane = tid & 63;
  const int qt = blockIdx.x & 15;
  const int h  = (blockIdx.x >> 4) & 15;
  const int b  = blockIdx.x >> 8;
  const int bS = b * SEQ;
  const int q0 = qt * 128 + wave * 32;
  const int l16 = lane & 15, quad = lane >> 4;
  const int sw = l16 & 7;
  u16* myP = &sP[wave][0];

  bf16x8 qf[2][4];
#pragma unroll
  for (int mb = 0; mb < 2; mb++)
#pragma unroll
    for (int kc = 0; kc < 4; kc++)
      qf[mb][kc] = *(const bf16x8*)&qkv[(size_t)(bS + q0 + mb*16 + l16) * QKV_N
                                        + h*HDIM + kc*32 + quad*8];

  f32x4 o[2][8] = {};
  float lrow[2] = {0.f, 0.f};
  const float sc2 = 0.08838834764831845f * 1.4426950408889634f;

  const u16* Kbase = qkv + (size_t)bS * QKV_N + D_MODEL;
  const u16* Vbase = vT + (size_t)b * HDIM * SEQ;

  const int kRowIn = lane >> 4;
  const int kChS   = lane & 15;
  const int vRowIn = lane >> 3;
  const int vChL   = (lane & 7) ^ (lane >> 3);

#define DMA_K(t, dst)                                                          \
  {                                                                            \
    const int _sk = (t) * 64;                                                  \
    _Pragma("unroll") for (int j = 0; j < 4; j++) {                            \
      const int i = wave * 4 + j;                                              \
      const int krow = i * 4 + kRowIn;                                         \
      const int kcl = kChS ^ (krow & 15);                                      \
      gload_lds16(&Kbase[(size_t)(_sk + krow) * QKV_N + kcl * 8],              \
                  &(dst)[i * 512]);                                            \
    }                                                                          \
  }
#define DMA_V(t)                                                               \
  {                                                                            \
    const int _sk = (t) * 64;                                                  \
    _Pragma("unroll") for (int j = 0; j < 4; j++) {                            \
      const int i = wave * 4 + j;                                              \
      const int d = i * 8 + vRowIn;                                            \
      gload_lds16(&Vbase[(size_t)d * SEQ + _sk + vChL * 8], &sV[i * 512]);     \
    }                                                                          \
  }

  DMA_K(0, sK[0]);
  DMA_V(0);
  __syncthreads();

  const int T = SEQ / 64;
  for (int t = 0; t < T; ++t) {
    const int cur = t & 1;
    if (t + 1 < T) DMA_K(t + 1, sK[cur ^ 1]);

    f32x4 sc[2][4];
#pragma unroll
    for (int nb = 0; nb < 4; nb++) {
      bf16x8 kf[4];
#pragma unroll
      for (int kc = 0; kc < 4; kc++)
        kf[kc] = *(const bf16x8*)&sK[cur][(nb*16 + l16) * 128 + (((kc*4 + quad) ^ l16) * 8)];
#pragma unroll
      for (int mb = 0; mb < 2; mb++) {
        f32x4 a = {0.f, 0.f, 0.f, 0.f};
#pragma unroll
        for (int kc = 0; kc < 4; kc++)
          a = __builtin_amdgcn_mfma_f32_16x16x32_bf16(kf[kc], qf[mb][kc], a, 0, 0, 0);
        sc[mb][nb] = a;
      }
    }

#pragma unroll
    for (int mb = 0; mb < 2; mb++)
#pragma unroll
      for (int nb = 0; nb < 4; nb++) {
        float p0 = __builtin_amdgcn_exp2f(sc[mb][nb][0] * sc2);
        float p1 = __builtin_amdgcn_exp2f(sc[mb][nb][1] * sc2);
        float p2 = __builtin_amdgcn_exp2f(sc[mb][nb][2] * sc2);
        float p3 = __builtin_amdgcn_exp2f(sc[mb][nb][3] * sc2);
        lrow[mb] += (p0 + p1) + (p2 + p3);
        uint32_t lo = (uint32_t)f2bf_fast(p0) | ((uint32_t)f2bf_fast(p1) << 16);
        uint32_t hi = (uint32_t)f2bf_fast(p2) | ((uint32_t)f2bf_fast(p3) << 16);
        uint2 w; w.x = lo; w.y = hi;
        const int pr = (nb*2 + (quad >> 1)) ^ sw;
        *(uint2*)&myP[(mb*16 + l16) * 64 + pr * 8 + (quad & 1) * 4] = w;
      }

    __syncthreads();

    bf16x8 pf[2][2];
#pragma unroll
    for (int mb = 0; mb < 2; mb++)
#pragma unroll
      for (int kc = 0; kc < 2; kc++)
        pf[mb][kc] = *(const bf16x8*)&myP[(mb*16 + l16) * 64 + (((kc*4 + quad) ^ sw) * 8)];
#pragma unroll
    for (int nb = 0; nb < 8; nb++) {
      bf16x8 vf[2];
#pragma unroll
      for (int kc = 0; kc < 2; kc++)
        vf[kc] = *(const bf16x8*)&sV[(nb*16 + l16) * 64 + (((kc*4 + quad) ^ (l16 & 7)) * 8)];
#pragma unroll
      for (int mb = 0; mb < 2; mb++)
#pragma unroll
        for (int kc = 0; kc < 2; kc++)
          o[mb][nb] = __builtin_amdgcn_mfma_f32_16x16x32_bf16(pf[mb][kc], vf[kc], o[mb][nb], 0, 0, 0);
    }

    __syncthreads();
    if (t + 1 < T) DMA_V(t + 1);
  }

#pragma unroll
  for (int mb = 0; mb < 2; mb++) {
    lrow[mb] += __shfl_xor(lrow[mb], 16, 64);
    lrow[mb] += __shfl_xor(lrow[mb], 32, 64);
  }
  float invl[2][4];
#pragma unroll
  for (int mb = 0; mb < 2; mb++)
#pragma unroll
    for (int r = 0; r < 4; r++)
      invl[mb][r] = 1.0f / __shfl(lrow[mb], quad * 4 + r, 64);

#pragma unroll
  for (int mb = 0; mb < 2; mb++)
#pragma unroll
    for (int nb = 0; nb < 8; nb++)
#pragma unroll
      for (int r = 0; r < 4; r++) {
        const int gq = q0 + mb*16 + quad*4 + r;
        const int gd = h * HDIM + nb*16 + l16;
        ctx[(size_t)(bS + gq) * D_MODEL + gd] = f2bf(o[mb][nb][r] * invl[mb][r]);
      }
}

// ---------------- launch ----------------
extern "C" void kernel_launch(void* const* d_in, const int* in_sizes, int n_in,
                              void* d_out, int out_size, void* d_ws, size_t ws_size,
                              hipStream_t stream) {
  const float* x  = (const float*)d_in[0];
  const float* wq = (const float*)d_in[1];
  const float* bq = (const float*)d_in[2];
  const float* wk = (const float*)d_in[3];
  const float* bk = (const float*)d_in[4];
  const float* wv = (const float*)d_in[5];
  const float* bv = (const float*)d_in[6];
  const float* wo = (const float*)d_in[7];
  const float* bo = (const float*)d_in[8];
  float* out = (float*)d_out;
  char* ws = (char*)d_ws;

  u16*   xb    = (u16*)(ws + 0);          // [4096,2048] bf16
  u16*   wqkvT = (u16*)(ws + 16777216);   // [2304,2048] bf16
  u16*   woT   = (u16*)(ws + 26214400);   // [2048,2048] bf16
  u16*   qkv   = (u16*)(ws + 34603008);   // [4096,2304] bf16
  u16*   vT    = (u16*)(ws + 53477376);   // [2,128,2048] bf16
  u16*   ctx   = (u16*)(ws + 54525952);   // [4096,2048] bf16
  float* biasq = (float*)(ws + 71303168); // [2304] f32

  prep_all<<<16897, 256, 0, stream>>>(x, xb, wq, wk, wv, wo, wqkvT, woT,
                                      bq, bk, bv, biasq);
  // merged QKV projection: 576 blocks, single-buffered (3 blocks/CU possible)
  gemm_bt<false><<<32 * 18, 256, 0, stream>>>(xb, wqkvT, biasq, qkv, nullptr, vT,
                                              NROWS, QKV_N, 18, D_MODEL);
  mqa_attn<<<BATCH * HEADS * (SEQ / 128), 256, 0, stream>>>(qkv, vT, ctx);
  // output projection: 512 blocks (2/CU uniform), double-buffered
  gemm_bt<true><<<32 * 16, 256, 0, stream>>>(ctx, woT, bo, nullptr, out, nullptr,
                                             NROWS, D_MODEL, 16, D_MODEL);
}